// Round 5
// baseline (175.079 us; speedup 1.0000x reference)
//
#include <hip/hip_runtime.h>

// SetCriterion loss (DETR-style) — fused reduction, v5.
//   v4 post-mortem: CRASH — staging enumerated 28 x 1KB logit chunks but the
//   tile is 14KB (14 chunks): LDS overrun + global OOB reads at tail tiles.
//   The 2-phase pipeline theory was never tested.
//   v5: same double-buffered async pipeline, with a correct flat chunk list:
//   21 chunks/tile (14 logits + 3 pdoa + 3 tdoa + 1 cls), round-robin over
//   the 4 waves (k = wv, wv+4, ... -> wave-uniform LDS base as gload_lds
//   requires). Issue next-tile staging BEFORE computing the current tile;
//   __syncthreads() provides the vmcnt(0) drain (depth-1 pipeline).
//
// Inputs (float32 unless noted):
//   d_in[0] pred_logits    [1.6M rows, 14]
//   d_in[1] pred_doa       [1.6M rows, 3]
//   d_in[2] target_doa     [1.6M rows, 3]
//   d_in[3] empty_weight   [14]
//   d_in[4] target_classes int32 [1.6M]
// Output: scalar float32.

constexpr int   kC     = 14;     // NUM_CLASSES + 1
constexpr int   kNoObj = 13;
constexpr float kWDoa  = 2.0f;
constexpr int   kBlock = 256;
constexpr int   kGrid  = 1250;   // 6250 tiles, 5 per block, exact
constexpr int   kRows  = 256;    // rows per tile (1 row/thread)

constexpr int kLogBytes = kRows * kC * 4;  // 14336 = 14 x 1KB chunks
constexpr int kDoaBytes = kRows * 3 * 4;   //  3072 =  3 x 1KB
constexpr int kClsBytes = kRows * 4;       //  1024 =  1 x 1KB
constexpr int kChunks   = 14 + 3 + 3 + 1;  // 21 chunks of 1KB per tile

typedef const unsigned int __attribute__((address_space(1)))* gas_t;
typedef unsigned int       __attribute__((address_space(3)))* las_t;

// async global->LDS DMA: per-lane global addr, wave-uniform LDS base,
// HW writes ldsbase + lane*16. Size must be a literal (16).
__device__ __forceinline__ void gl_lds16(const void* g, void* l) {
    __builtin_amdgcn_global_load_lds((gas_t)g, (las_t)l, 16, 0, 0);
}

__global__ __launch_bounds__(kBlock) void loss_main(
    const float* __restrict__ logits,   // [R,14]
    const float* __restrict__ pdoa,     // [R,3]
    const float* __restrict__ tdoa,     // [R,3]
    const float* __restrict__ ew,       // [14]
    const int*   __restrict__ tcls,     // [R]
    int nrows,
    float* __restrict__ part_wce,       // [kGrid]
    float* __restrict__ part_abs,       // [kGrid]
    unsigned int* __restrict__ part_cnt)// [kGrid]
{
    __shared__ float lx [2][kRows * kC];   // 2 x 14336 B (linear: gload_lds dest)
    __shared__ float lpd[2][kRows * 3];    // 2 x  3072 B
    __shared__ float ltd[2][kRows * 3];    // 2 x  3072 B
    __shared__ int   lcl[2][kRows];        // 2 x  1024 B   -> 43008 B total
    __shared__ float        rw[kBlock / 64];
    __shared__ float        ra[kBlock / 64];
    __shared__ unsigned int rc[kBlock / 64];

    const int t    = threadIdx.x;
    const int lane = t & 63;
    const int wv   = t >> 6;

    float        s_wce = 0.f;
    float        s_abs = 0.f;
    unsigned int cnt   = 0u;

    const int ntiles = nrows / kRows;      // 6250

    // stage tile -> buffer b. 21 x 1KB chunks, round-robin over 4 waves.
    // k is wave-uniform (k = wv + 4c) -> wave-uniform LDS dest as required.
    auto stage = [&](int tile, int b) {
        const char* lg = (const char*)logits + (size_t)tile * kLogBytes;
        const char* pg = (const char*)pdoa   + (size_t)tile * kDoaBytes;
        const char* tg = (const char*)tdoa   + (size_t)tile * kDoaBytes;
        const char* cg = (const char*)tcls   + (size_t)tile * kClsBytes;
        for (int k = wv; k < kChunks; k += 4) {
            const char* src;
            char*       dst;
            if (k < 14)      { src = lg + (size_t)k * 1024;
                               dst = (char*)lx[b]  + k * 1024; }
            else if (k < 17) { src = pg + (size_t)(k - 14) * 1024;
                               dst = (char*)lpd[b] + (k - 14) * 1024; }
            else if (k < 20) { src = tg + (size_t)(k - 17) * 1024;
                               dst = (char*)ltd[b] + (k - 17) * 1024; }
            else             { src = cg;
                               dst = (char*)lcl[b]; }
            gl_lds16(src + lane * 16, dst);
        }
    };

    // prologue: stage first tile, drain, enter steady state
    int cur = 0;
    stage(blockIdx.x, 0);
    __syncthreads();                       // vmcnt(0) drain + barrier

    for (int tile = blockIdx.x; tile < ntiles; tile += kGrid) {
        const int nxt = tile + kGrid;
        if (nxt < ntiles) stage(nxt, cur ^ 1);   // issue async loads FIRST

        // ---- compute current tile from LDS ----
        const int tc = lcl[cur][t];
        float x[kC];
#pragma unroll
        for (int j = 0; j < kC; ++j) x[j] = lx[cur][t * kC + j];

        float m = x[0];
#pragma unroll
        for (int j = 1; j < kC; ++j) m = fmaxf(m, x[j]);
        float s  = 0.f;
        float xt = 0.f;                    // static-index extract (stays in regs)
#pragma unroll
        for (int j = 0; j < kC; ++j) {
            s += __expf(x[j] - m);
            xt = (j == tc) ? x[j] : xt;
        }
        s_wce += ew[tc] * (m + __logf(s) - xt);   // 56B table, L1-resident

        const float d = fabsf(lpd[cur][3 * t + 0] - ltd[cur][3 * t + 0])
                      + fabsf(lpd[cur][3 * t + 1] - ltd[cur][3 * t + 1])
                      + fabsf(lpd[cur][3 * t + 2] - ltd[cur][3 * t + 2]);
        if (tc != kNoObj) { s_abs += d; cnt += 1u; }

        // drain staged loads for tile+kGrid AND fence buffer reuse
        __syncthreads();
        cur ^= 1;
    }

    // ---- wave64 butterfly + cross-wave, one partial per block ----
#pragma unroll
    for (int o = 32; o > 0; o >>= 1) {
        s_wce += __shfl_down(s_wce, o);
        s_abs += __shfl_down(s_abs, o);
        cnt   += __shfl_down(cnt, o);
    }
    if (lane == 0) { rw[wv] = s_wce; ra[wv] = s_abs; rc[wv] = cnt; }
    __syncthreads();
    if (t == 0) {
        float tw = 0.f, ta = 0.f; unsigned int tn = 0u;
#pragma unroll
        for (int i = 0; i < kBlock / 64; ++i) { tw += rw[i]; ta += ra[i]; tn += rc[i]; }
        part_wce[blockIdx.x] = tw;         // plain stores, no atomics
        part_abs[blockIdx.x] = ta;
        part_cnt[blockIdx.x] = tn;
    }
}

__global__ __launch_bounds__(kBlock) void finalize(
    const float* __restrict__ part_wce,
    const float* __restrict__ part_abs,
    const unsigned int* __restrict__ part_cnt,
    float* __restrict__ out, int nrows, int nparts)
{
    double w = 0.0, a = 0.0;
    unsigned long long c = 0ull;
    for (int i = threadIdx.x; i < nparts; i += kBlock) {
        w += (double)part_wce[i];
        a += (double)part_abs[i];
        c += (unsigned long long)part_cnt[i];
    }
#pragma unroll
    for (int o = 32; o > 0; o >>= 1) {
        w += __shfl_down(w, o);
        a += __shfl_down(a, o);
        c += __shfl_down(c, o);
    }
    __shared__ double sw[kBlock / 64], sa[kBlock / 64];
    __shared__ unsigned long long sc[kBlock / 64];
    const int lane = threadIdx.x & 63, wid = threadIdx.x >> 6;
    if (lane == 0) { sw[wid] = w; sa[wid] = a; sc[wid] = c; }
    __syncthreads();
    if (threadIdx.x == 0) {
        double tw = 0.0, ta = 0.0;
        unsigned long long tc = 0ull;
#pragma unroll
        for (int i = 0; i < kBlock / 64; ++i) { tw += sw[i]; ta += sa[i]; tc += sc[i]; }
        const double lc = tw / (double)nrows;
        const double ld = (tc > 0ull) ? (ta / (3.0 * (double)tc)) : 0.0;
        out[0] = (float)(lc + (double)kWDoa * ld);
    }
}

extern "C" void kernel_launch(void* const* d_in, const int* in_sizes, int n_in,
                              void* d_out, int out_size, void* d_ws, size_t ws_size,
                              hipStream_t stream) {
    const float* logits = (const float*)d_in[0];
    const float* pdoa   = (const float*)d_in[1];
    const float* tdoa   = (const float*)d_in[2];
    const float* ew     = (const float*)d_in[3];
    const int*   tcls   = (const int*)d_in[4];
    float*       out    = (float*)d_out;

    float*        pw = (float*)d_ws;
    float*        pa = pw + kGrid;
    unsigned int* pc = (unsigned int*)(pa + kGrid);

    const int nrows = in_sizes[4];   // 1,600,000 = 6250 * 256

    loss_main<<<kGrid, kBlock, 0, stream>>>(logits, pdoa, tdoa, ew, tcls, nrows,
                                            pw, pa, pc);
    finalize<<<1, kBlock, 0, stream>>>(pw, pa, pc, out, nrows, kGrid);
}